// Round 1
// baseline (1895.275 us; speedup 1.0000x reference)
//
#include <hip/hip_runtime.h>

namespace {

constexpr int Tn = 4096;
constexpr int Dn = 64;
constexpr int BQ = 64;
constexpr int BK = 64;
constexpr int STR = 68;           // LDS row stride in floats: 16B-aligned, 2-way-max bank aliasing
constexpr float SCALE = 0.125f;   // 1/sqrt(64)

// One block per (batch, 64-row Q tile). 256 threads = 4 waves.
// Thread (ty,tx), ty=tid>>4 in 0..15, tx=tid&15.
// S-compute / softmax / PV rows owned: r_i = ty + 16*i (i=0..3)  -> m/l state lives in regs
// S cols: c_j = tx + 16*j ; O dims: d = tx*4 .. tx*4+3
__launch_bounds__(256, 2)
__global__ void fa_fwd(const float* __restrict__ Q,
                       const float* __restrict__ K,
                       const float* __restrict__ V,
                       float* __restrict__ O) {
  __shared__ __align__(16) float Qs[BQ * STR];
  __shared__ __align__(16) float KVs[BK * STR];   // K tile, then reused for V tile
  __shared__ __align__(16) float Ps[BQ * STR];

  const int bid = blockIdx.x;
  // Work-balance pairing: blocks i and i+256 (likely same CU on 2nd fill pass)
  // get qt and 63-qt -> ~65 k-tiles per pair.
  int b, qt;
  if (bid < 256) { b = bid & 7; qt = bid >> 3; }
  else           { b = bid & 7; qt = 63 - ((bid - 256) >> 3); }

  const int tid = threadIdx.x;
  const int ty = tid >> 4;
  const int tx = tid & 15;

  const size_t base = (size_t)b * Tn * Dn;
  const float* Qb = Q + base + (size_t)qt * BQ * Dn;
  const float* Kb = K + base;
  const float* Vb = V + base;
  float* Ob = O + base + (size_t)qt * BQ * Dn;

  // ---- load Q tile: 64x64 floats = 1024 float4, 4 per thread, coalesced ----
  #pragma unroll
  for (int i = 0; i < 4; ++i) {
    int idx = tid + 256 * i;
    int row = idx >> 4, c4 = idx & 15;
    float4 t = reinterpret_cast<const float4*>(Qb)[idx];
    float* d = &Qs[row * STR + c4 * 4];
    d[0] = t.x; d[1] = t.y; d[2] = t.z; d[3] = t.w;
  }

  float m_i[4], l_i[4], o_[4][4];
  #pragma unroll
  for (int i = 0; i < 4; ++i) {
    m_i[i] = -1e30f;
    l_i[i] = 0.0f;
    #pragma unroll
    for (int j = 0; j < 4; ++j) o_[i][j] = 0.0f;
  }
  __syncthreads();

  for (int kt = 0; kt <= qt; ++kt) {
    // ---- load K tile into KVs ----
    const float* Ksrc = Kb + (size_t)kt * BK * Dn;
    #pragma unroll
    for (int i = 0; i < 4; ++i) {
      int idx = tid + 256 * i;
      int row = idx >> 4, c4 = idx & 15;
      float4 t = reinterpret_cast<const float4*>(Ksrc)[idx];
      float* d = &KVs[row * STR + c4 * 4];
      d[0] = t.x; d[1] = t.y; d[2] = t.z; d[3] = t.w;
    }
    __syncthreads();

    // ---- S = Q K^T, 4x4 per thread, float4 along D ----
    float s[4][4];
    #pragma unroll
    for (int i = 0; i < 4; ++i)
      #pragma unroll
      for (int j = 0; j < 4; ++j) s[i][j] = 0.0f;

    #pragma unroll
    for (int d4 = 0; d4 < 16; ++d4) {
      float4 qv[4], kv[4];
      #pragma unroll
      for (int i = 0; i < 4; ++i)
        qv[i] = *reinterpret_cast<const float4*>(&Qs[(ty + 16 * i) * STR + 4 * d4]);
      #pragma unroll
      for (int j = 0; j < 4; ++j)
        kv[j] = *reinterpret_cast<const float4*>(&KVs[(tx + 16 * j) * STR + 4 * d4]);
      #pragma unroll
      for (int i = 0; i < 4; ++i)
        #pragma unroll
        for (int j = 0; j < 4; ++j) {
          s[i][j] += qv[i].x * kv[j].x;
          s[i][j] += qv[i].y * kv[j].y;
          s[i][j] += qv[i].z * kv[j].z;
          s[i][j] += qv[i].w * kv[j].w;
        }
    }

    // ---- scale + causal mask (diagonal tile only) ----
    if (kt == qt) {
      #pragma unroll
      for (int i = 0; i < 4; ++i)
        #pragma unroll
        for (int j = 0; j < 4; ++j) {
          int row = ty + 16 * i, col = tx + 16 * j;
          s[i][j] = (col > row) ? -1e30f : s[i][j] * SCALE;
        }
    } else {
      #pragma unroll
      for (int i = 0; i < 4; ++i)
        #pragma unroll
        for (int j = 0; j < 4; ++j) s[i][j] *= SCALE;
    }

    // ---- online softmax, state in registers, reduce across 16 tx lanes ----
    float alpha[4];
    #pragma unroll
    for (int i = 0; i < 4; ++i) {
      float mx = fmaxf(fmaxf(s[i][0], s[i][1]), fmaxf(s[i][2], s[i][3]));
      #pragma unroll
      for (int off = 1; off < 16; off <<= 1)
        mx = fmaxf(mx, __shfl_xor(mx, off));
      float mnew = fmaxf(m_i[i], mx);
      alpha[i] = __expf(m_i[i] - mnew);
      m_i[i] = mnew;
      float ps = 0.0f;
      #pragma unroll
      for (int j = 0; j < 4; ++j) {
        float p = __expf(s[i][j] - mnew);
        s[i][j] = p;
        ps += p;
      }
      #pragma unroll
      for (int off = 1; off < 16; off <<= 1)
        ps += __shfl_xor(ps, off);
      l_i[i] = l_i[i] * alpha[i] + ps;
      // write P row fragment
      #pragma unroll
      for (int j = 0; j < 4; ++j)
        Ps[(ty + 16 * i) * STR + tx + 16 * j] = s[i][j];
    }
    __syncthreads();   // K reads + P writes complete

    // ---- load V tile into KVs (reuse) ----
    const float* Vsrc = Vb + (size_t)kt * BK * Dn;
    #pragma unroll
    for (int i = 0; i < 4; ++i) {
      int idx = tid + 256 * i;
      int row = idx >> 4, c4 = idx & 15;
      float4 t = reinterpret_cast<const float4*>(Vsrc)[idx];
      float* d = &KVs[row * STR + c4 * 4];
      d[0] = t.x; d[1] = t.y; d[2] = t.z; d[3] = t.w;
    }
    __syncthreads();

    // ---- O = O*alpha + P V ----
    #pragma unroll
    for (int i = 0; i < 4; ++i)
      #pragma unroll
      for (int j = 0; j < 4; ++j) o_[i][j] *= alpha[i];

    #pragma unroll
    for (int c4 = 0; c4 < 16; ++c4) {
      float4 vv[4];
      #pragma unroll
      for (int cc = 0; cc < 4; ++cc)
        vv[cc] = *reinterpret_cast<const float4*>(&KVs[(c4 * 4 + cc) * STR + tx * 4]);
      #pragma unroll
      for (int i = 0; i < 4; ++i) {
        float4 pv = *reinterpret_cast<const float4*>(&Ps[(ty + 16 * i) * STR + c4 * 4]);
        o_[i][0] += pv.x * vv[0].x; o_[i][1] += pv.x * vv[0].y;
        o_[i][2] += pv.x * vv[0].z; o_[i][3] += pv.x * vv[0].w;
        o_[i][0] += pv.y * vv[1].x; o_[i][1] += pv.y * vv[1].y;
        o_[i][2] += pv.y * vv[1].z; o_[i][3] += pv.y * vv[1].w;
        o_[i][0] += pv.z * vv[2].x; o_[i][1] += pv.z * vv[2].y;
        o_[i][2] += pv.z * vv[2].z; o_[i][3] += pv.z * vv[2].w;
        o_[i][0] += pv.w * vv[3].x; o_[i][1] += pv.w * vv[3].y;
        o_[i][2] += pv.w * vv[3].z; o_[i][3] += pv.w * vv[3].w;
      }
    }
    __syncthreads();   // V/P reads done before next tile overwrites
  }

  // ---- epilogue: normalize + store ----
  #pragma unroll
  for (int i = 0; i < 4; ++i) {
    float inv = 1.0f / l_i[i];
    float4 r;
    r.x = o_[i][0] * inv; r.y = o_[i][1] * inv;
    r.z = o_[i][2] * inv; r.w = o_[i][3] * inv;
    *reinterpret_cast<float4*>(&Ob[(ty + 16 * i) * Dn + tx * 4]) = r;
  }
}

}  // namespace

extern "C" void kernel_launch(void* const* d_in, const int* in_sizes, int n_in,
                              void* d_out, int out_size, void* d_ws, size_t ws_size,
                              hipStream_t stream) {
  const float* q = (const float*)d_in[0];
  const float* k = (const float*)d_in[1];
  const float* v = (const float*)d_in[2];
  float* out = (float*)d_out;
  fa_fwd<<<dim3(512), dim3(256), 0, stream>>>(q, k, v, out);
}

// Round 2
// 170.230 us; speedup vs baseline: 11.1336x; 11.1336x over previous
//
#include <hip/hip_runtime.h>

namespace {

constexpr int Tn = 4096;
constexpr int Dn = 64;
constexpr float SCALE = 0.125f;   // 1/sqrt(64)
constexpr int RS = 72;            // ushort row stride for 64-wide bf16 tiles (144 B, 16B-aligned)

typedef short bf16x8 __attribute__((ext_vector_type(8)));
typedef float f32x4 __attribute__((ext_vector_type(4)));

// f32 -> bf16 round-to-nearest-even, packed pair (lo = a, hi = b)
__device__ inline unsigned int pack2(float a, float b) {
  unsigned int ua = __builtin_bit_cast(unsigned int, a);
  unsigned int ub = __builtin_bit_cast(unsigned int, b);
  ua = (ua + 0x7FFFu + ((ua >> 16) & 1u)) >> 16;
  ub = (ub + 0x7FFFu + ((ub >> 16) & 1u)) & 0xFFFF0000u;
  return ua | ub;
}

// One block per (batch, 64-row Q tile): 256 threads = 4 waves, wave w owns Q rows w*16..w*16+15.
// Orientation: S^T = K*Q^T so each lane's softmax row (qrow = lane&15) is replicated across quads:
// row reductions are 2 shfl_xor. P round-trips LDS within the wave (no barrier). PV: A=P, B=V^T.
__launch_bounds__(256, 2)
__global__ void fa_mfma(const float* __restrict__ Q,
                        const float* __restrict__ K,
                        const float* __restrict__ V,
                        float* __restrict__ O) {
  __shared__ __align__(16) unsigned short Klds[64 * RS];  // K tile, natural [key][d]
  __shared__ __align__(16) unsigned short Vt[64 * RS];    // V tile, transposed [d][key]
  __shared__ __align__(16) unsigned short Plds[64 * RS];  // P, [qrow][key]; wave-private rows

  const int bid = blockIdx.x;
  // causal work-balance pairing: qt and 63-qt
  int b, qt;
  if (bid < 256) { b = bid & 7; qt = bid >> 3; }
  else           { b = bid & 7; qt = 63 - ((bid - 256) >> 3); }

  const int tid  = threadIdx.x;
  const int w    = tid >> 6;     // wave 0..3
  const int lane = tid & 63;
  const int quad = lane >> 4;
  const int lc   = lane & 15;

  const size_t base = (size_t)b * Tn * Dn;
  const float* Qb = Q + base + (size_t)qt * 64 * Dn;
  const float* Kb = K + base;
  const float* Vb = V + base;
  float* Ob = O + base + (size_t)qt * 64 * Dn;

  // ---- Q fragments (B-operand of S^T): lane holds Q[qrow=w*16+lc][ks*32+quad*8+j] ----
  bf16x8 qf[2];
  {
    const float* qrow = Qb + (w * 16 + lc) * Dn + quad * 8;
    #pragma unroll
    for (int ks = 0; ks < 2; ++ks) {
      float4 x = *(const float4*)(qrow + ks * 32);
      float4 y = *(const float4*)(qrow + ks * 32 + 4);
      uint4 u = make_uint4(pack2(x.x, x.y), pack2(x.z, x.w),
                           pack2(y.x, y.y), pack2(y.z, y.w));
      qf[ks] = __builtin_bit_cast(bf16x8, u);
    }
  }

  float m_i = -1e30f, l_i = 0.0f;
  f32x4 o[4];
  #pragma unroll
  for (int nt = 0; nt < 4; ++nt) o[nt] = f32x4{0.f, 0.f, 0.f, 0.f};

  for (int kt = 0; kt <= qt; ++kt) {
    __syncthreads();   // previous tile's Klds/Vt reads complete

    // ---- stage K tile: natural layout, f32x4 coalesced -> bf16x4 ds_write_b64 ----
    {
      const float4* Ks4 = (const float4*)(Kb + (size_t)kt * 64 * Dn);
      #pragma unroll
      for (int i = 0; i < 4; ++i) {
        int idx = tid + 256 * i;
        int row = idx >> 4, c4 = idx & 15;
        float4 t = Ks4[idx];
        *(uint2*)&Klds[row * RS + c4 * 4] = make_uint2(pack2(t.x, t.y), pack2(t.z, t.w));
      }
    }
    // ---- stage V tile transposed: each lane gathers column d=lane via 16 coalesced row reads ----
    {
      const float* Vs = Vb + (size_t)kt * 64 * Dn;
      float tmp[16];
      #pragma unroll
      for (int it = 0; it < 16; ++it)
        tmp[it] = Vs[(w * 16 + it) * Dn + lane];
      unsigned int pk[8];
      #pragma unroll
      for (int p = 0; p < 8; ++p) pk[p] = pack2(tmp[2 * p], tmp[2 * p + 1]);
      *(uint4*)&Vt[lane * RS + w * 16]     = make_uint4(pk[0], pk[1], pk[2], pk[3]);
      *(uint4*)&Vt[lane * RS + w * 16 + 8] = make_uint4(pk[4], pk[5], pk[6], pk[7]);
    }
    __syncthreads();   // tiles visible to all waves

    // ---- S^T tiles: M=key (4 tiles of 16), N=qrow(16), K-dim=64 ----
    f32x4 st[4];
    #pragma unroll
    for (int t = 0; t < 4; ++t) {
      f32x4 c = {0.f, 0.f, 0.f, 0.f};
      #pragma unroll
      for (int ks = 0; ks < 2; ++ks) {
        bf16x8 a = *(const bf16x8*)&Klds[(t * 16 + lc) * RS + ks * 32 + quad * 8];
        c = __builtin_amdgcn_mfma_f32_16x16x32_bf16(a, qf[ks], c, 0, 0, 0);
      }
      st[t] = c;
    }

    // ---- online softmax: lane owns qrow = w*16+lc, holds keys 16t+quad*4+r ----
    const bool diag = (kt == qt);
    float p16[16];
    #pragma unroll
    for (int t = 0; t < 4; ++t)
      #pragma unroll
      for (int r = 0; r < 4; ++r) {
        int key_l = 16 * t + quad * 4 + r;
        float v = st[t][r] * SCALE;
        if (diag && key_l > w * 16 + lc) v = -1e30f;
        p16[4 * t + r] = v;
      }
    float tmax = p16[0];
    #pragma unroll
    for (int i = 1; i < 16; ++i) tmax = fmaxf(tmax, p16[i]);
    tmax = fmaxf(tmax, __shfl_xor(tmax, 16));
    tmax = fmaxf(tmax, __shfl_xor(tmax, 32));
    float mnew = fmaxf(m_i, tmax);
    float alpha = __expf(m_i - mnew);
    m_i = mnew;

    float s = 0.0f;
    unsigned int pp[8];
    #pragma unroll
    for (int t = 0; t < 4; ++t) {
      float e0 = __expf(p16[4 * t + 0] - mnew);
      float e1 = __expf(p16[4 * t + 1] - mnew);
      float e2 = __expf(p16[4 * t + 2] - mnew);
      float e3 = __expf(p16[4 * t + 3] - mnew);
      s += (e0 + e1) + (e2 + e3);
      pp[2 * t]     = pack2(e0, e1);
      pp[2 * t + 1] = pack2(e2, e3);
    }
    s += __shfl_xor(s, 16);
    s += __shfl_xor(s, 32);
    l_i = l_i * alpha + s;

    // write P rows (wave-private): key block 16t+quad*4 .. +3, packed bf16x4
    #pragma unroll
    for (int t = 0; t < 4; ++t)
      *(uint2*)&Plds[(w * 16 + lc) * RS + 16 * t + quad * 4] =
          make_uint2(pp[2 * t], pp[2 * t + 1]);

    // ---- rescale O by alpha of its rows (rows quad*4+r; alpha lives at lane quad*4+r) ----
    float av[4];
    #pragma unroll
    for (int r = 0; r < 4; ++r) av[r] = __shfl(alpha, quad * 4 + r);
    #pragma unroll
    for (int nt = 0; nt < 4; ++nt)
      #pragma unroll
      for (int r = 0; r < 4; ++r) o[nt][r] *= av[r];

    // ---- PV: A = P (own wave's rows; same-wave LDS round-trip, no barrier), B = V^T ----
    #pragma unroll
    for (int ks = 0; ks < 2; ++ks) {
      bf16x8 a = *(const bf16x8*)&Plds[(w * 16 + lc) * RS + ks * 32 + quad * 8];
      #pragma unroll
      for (int nt = 0; nt < 4; ++nt) {
        bf16x8 bfr = *(const bf16x8*)&Vt[(nt * 16 + lc) * RS + ks * 32 + quad * 8];
        o[nt] = __builtin_amdgcn_mfma_f32_16x16x32_bf16(a, bfr, o[nt], 0, 0, 0);
      }
    }
  }

  // ---- epilogue: rows quad*4+r, cols nt*16+lc ----
  float linv[4];
  #pragma unroll
  for (int r = 0; r < 4; ++r) linv[r] = 1.0f / __shfl(l_i, quad * 4 + r);
  #pragma unroll
  for (int r = 0; r < 4; ++r) {
    float* orow = Ob + (w * 16 + quad * 4 + r) * Dn + lc;
    #pragma unroll
    for (int nt = 0; nt < 4; ++nt)
      orow[nt * 16] = o[nt][r] * linv[r];
  }
}

}  // namespace

extern "C" void kernel_launch(void* const* d_in, const int* in_sizes, int n_in,
                              void* d_out, int out_size, void* d_ws, size_t ws_size,
                              hipStream_t stream) {
  const float* q = (const float*)d_in[0];
  const float* k = (const float*)d_in[1];
  const float* v = (const float*)d_in[2];
  float* out = (float*)d_out;
  fa_mfma<<<dim3(512), dim3(256), 0, stream>>>(q, k, v, out);
}